// Round 6
// baseline (671.519 us; speedup 1.0000x reference)
//
#include <hip/hip_runtime.h>
#include <hip/hip_bf16.h>
#include <stdint.h>

typedef unsigned short u16;
typedef __attribute__((ext_vector_type(8))) short bf16x8;   // 8 bf16 (4 VGPRs)
typedef __attribute__((ext_vector_type(4))) float f32x4;    // 4 fp32 acc

#define TOKENS   16384
#define HIDDEN   2048
#define QKV_OUT  3072
#define NEXP     4

#define BM 256
#define BN 256
#define BK 64
#define NT       (HIDDEN / BK)         // 32 K-tiles
#define RT_TILES (TOKENS / BM)         // 64
#define CT_TILES (QKV_OUT / BN)        // 12
#define NBLK     (RT_TILES * CT_TILES) // 768
#define TSZ      (256 * 64)            // u16 per 32KB operand buffer

// ---------------- fp32 -> bf16 (RNE) conversion, single-pass fused ----------------

__device__ __forceinline__ uint32_t f2bf(float f) {
  uint32_t u = __builtin_bit_cast(uint32_t, f);
  return (u + 0x7FFFu + ((u >> 16) & 1u)) >> 16;   // round-nearest-even
}

#define NX8 ((long)TOKENS * HIDDEN / 8)            // 4,194,304
#define NW8 ((long)NEXP * QKV_OUT * HIDDEN / 8)    // 3,145,728

__global__ void cvt_all(const float* __restrict__ x, const float* __restrict__ W,
                        u16* __restrict__ Xb, u16* __restrict__ Wb) {
  long gid = (long)blockIdx.x * blockDim.x + threadIdx.x;   // one 16B-out chunk/thread
  const float* src; u16* dst; long p;
  if (gid < NX8) { src = x;  dst = Xb; p = gid; }
  else           { src = W;  dst = Wb; p = gid - NX8; }
  const float4* s = (const float4*)src + p * 2;
  float4 a = s[0], b = s[1];
  uint4 q;
  q.x = f2bf(a.x) | (f2bf(a.y) << 16);
  q.y = f2bf(a.z) | (f2bf(a.w) << 16);
  q.z = f2bf(b.x) | (f2bf(b.y) << 16);
  q.w = f2bf(b.z) | (f2bf(b.w) << 16);
  ((uint4*)dst)[p] = q;
}

// ---------------- async global -> LDS, 16B per lane ----------------

typedef const __attribute__((address_space(1))) void* gptr_t;
typedef __attribute__((address_space(3))) void* lptr_t;

// HW-verified (R3: SQ_LDS_BANK_CONFLICT == 0): within a 256x64 u16 buffer,
// phys 16B-chunk of logical chunk c in row r is c ^ (r&7). gload_lds writes
// linearly, so the global SOURCE column is pre-swizzled (rule #21).
__device__ __forceinline__ int lds_off(int row, int chunk) {
  return row * BK + ((chunk ^ (row & 7)) << 3);
}

// stage one 64-row quarter q of an operand tile (K-tile kt) into Lbuf.
// 512 threads x 16B = 8KB = 64 rows. One gload per wave (vmcnt +1/wave).
__device__ __forceinline__ void stage_q(const u16* gsrc, u16* Lbuf, int kt,
                                        int q, int tid) {
  const int r    = tid >> 3;                    // 0..63 row within quarter
  const int schk = (tid & 7) ^ (r & 7);         // pre-swizzled source chunk
  const u16* g = gsrc + (size_t)(q * 64 + r) * HIDDEN + kt * BK + schk * 8;
  u16* dst = Lbuf + (q * 64 + (tid >> 6) * 8) * BK;   // wave-uniform base
  __builtin_amdgcn_global_load_lds((gptr_t)g, (lptr_t)dst, 16, 0, 0);
}

// stage a FULL 256x64 tile pair slot (A or B) = 8 quarters across A+B callers.
__device__ __forceinline__ void stage_tile(const u16* gsrc, u16* Lbuf, int kt, int tid) {
#pragma unroll
  for (int q = 0; q < 4; ++q) stage_q(gsrc, Lbuf, kt, q, tid);
}

// ---------------- grouped bf16 GEMM, 256x256 8-phase (T1+T2+T3+T4+T5) ----------------
// R6 schedule: WHOLE-TILE restage in the single phase after the buffer's last
// read.  p0 stages buf1<-t1 (first read p4); p4 stages buf0<-t0+2 (first read
// next p0).  Every vmcnt(0) therefore waits only on loads issued >=3 phases
// (~2400 cyc) earlier -> stall-free even at HBM-miss latency (~900 cyc).
// R5's failure mode (vmcnt retiring 1-phase-old loads => 8-phase degenerated
// to 2-phase perf, m218's drain0 signature) is structurally eliminated.
// Staging buffer is always FULLY DISJOINT from the phase's read buffer.

__global__ void __launch_bounds__(512, 2)
moe_qkv_gemm(const u16* __restrict__ Xb,   // [TOKENS][HIDDEN] bf16
             const u16* __restrict__ Wb,   // [NEXP][QKV_OUT][HIDDEN] bf16
             const int* __restrict__ mm,   // [TOKENS] sorted expert ids
             float* __restrict__ out) {    // [TOKENS][QKV_OUT] fp32
  extern __shared__ u16 Lds[];   // [buf0.A][buf0.B][buf1.A][buf1.B], 4 x 32KB

  // XCD-aware bijective swizzle (768 % 8 == 0), rt-major chunks per XCD.
  const int cpx = NBLK >> 3;                    // 96
  int bid = blockIdx.x;
  int swz = (bid & 7) * cpx + (bid >> 3);
  const int rt = swz / CT_TILES;
  const int ct = swz % CT_TILES;
  const int row0 = rt * BM;
  const int col0 = ct * BN;

  const int tid  = threadIdx.x;
  const int lane = tid & 63;
  const int wid  = tid >> 6;
  const int wr   = wid >> 2;      // 0..1 : 128-row slab
  const int wc   = wid & 3;       // 0..3 : 64-col slab

  const int e_lo = mm[row0];
  const int e_hi = mm[row0 + BM - 1];

  f32x4 acc[8][4];
#pragma unroll
  for (int m = 0; m < 8; ++m)
#pragma unroll
    for (int n = 0; n < 4; ++n) acc[m][n] = (f32x4){0.f, 0.f, 0.f, 0.f};

  if (e_lo == e_hi) {
    // ================= fast path: uniform expert (>=61/64 row-tiles) ==========
    const u16* Asrc = Xb + (size_t)row0 * HIDDEN;
    const u16* Bsrc = Wb + (size_t)e_lo * QKV_OUT * HIDDEN + (size_t)col0 * HIDDEN;

    u16* A0 = Lds;            u16* B0 = Lds + TSZ;
    u16* A1 = Lds + 2 * TSZ;  u16* B1 = Lds + 3 * TSZ;

    // ---- prologue: tile0 -> buf0; one cold-latency drain (once per block)
    {
      stage_tile(Asrc, A0, 0, tid);
      stage_tile(Bsrc, B0, 0, tid);
      asm volatile("s_waitcnt vmcnt(0)" ::: "memory");
      __builtin_amdgcn_s_barrier();
      __builtin_amdgcn_sched_barrier(0);
    }

    // One phase: {8 ds_read ; [stage next tile] ; [vmcnt(0)] ; barrier ;
    //             lgkmcnt(0)+sched_barrier ; setprio(1) 16xMFMA setprio(0) ; barrier}
#define PHASE(LA, LB, KS, MH, STAGE_CODE, VMW)                                     \
    {                                                                              \
      const int chunk = (KS) * 4 + (lane >> 4);                                    \
      bf16x8 af[4], bfr[4];                                                        \
      _Pragma("unroll")                                                            \
      for (int m = 0; m < 4; ++m)                                                  \
        af[m] = *(const bf16x8*)&(LA)[lds_off(wr * 128 + ((MH) * 4 + m) * 16 + (lane & 15), chunk)]; \
      _Pragma("unroll")                                                            \
      for (int n = 0; n < 4; ++n)                                                  \
        bfr[n] = *(const bf16x8*)&(LB)[lds_off(wc * 64 + n * 16 + (lane & 15), chunk)]; \
      STAGE_CODE;                                                                  \
      VMW;                                                                         \
      __builtin_amdgcn_s_barrier();                                                \
      asm volatile("s_waitcnt lgkmcnt(0)" ::: "memory");                           \
      __builtin_amdgcn_sched_barrier(0);                                           \
      __builtin_amdgcn_s_setprio(1);                                               \
      _Pragma("unroll")                                                            \
      for (int m = 0; m < 4; ++m)                                                  \
        _Pragma("unroll")                                                          \
        for (int n = 0; n < 4; ++n)                                                \
          acc[(MH) * 4 + m][n] = __builtin_amdgcn_mfma_f32_16x16x32_bf16(          \
              af[m], bfr[n], acc[(MH) * 4 + m][n], 0, 0, 0);                       \
      __builtin_amdgcn_s_setprio(0);                                               \
      __builtin_amdgcn_s_barrier();                                                \
      __builtin_amdgcn_sched_barrier(0);                                           \
    }

#define VM0 asm volatile("s_waitcnt vmcnt(0)" ::: "memory")

    // ---- main loop: 15 iterations x 2 K-tiles, unconditional stages.
    // vmcnt ledger (per wave): at p3's VM0, outstanding == p0's 8 stages
    // (3 phases old).  At p7's VM0, outstanding == p4's 8 (3 phases old).
    for (int it = 0; it < 15; ++it) {
      const int t1 = 2 * it + 1, t2 = 2 * it + 2;
      // tile 2it in buf0; p0 restages buf1 (last read: prev p7)
      PHASE(A0, B0, 0, 0, { stage_tile(Asrc, A1, t1, tid);
                            stage_tile(Bsrc, B1, t1, tid); }, );
      PHASE(A0, B0, 0, 1, { }, );
      PHASE(A0, B0, 1, 0, { }, );
      PHASE(A0, B0, 1, 1, { }, VM0);
      // tile 2it+1 in buf1; p4 restages buf0 (last read: p3)
      PHASE(A1, B1, 0, 0, { stage_tile(Asrc, A0, t2, tid);
                            stage_tile(Bsrc, B0, t2, tid); }, );
      PHASE(A1, B1, 0, 1, { }, );
      PHASE(A1, B1, 1, 0, { }, );
      PHASE(A1, B1, 1, 1, { }, VM0);
    }
    // ---- peeled final iteration: tiles 30 (buf0) / 31 (buf1), no t2 stage
    PHASE(A0, B0, 0, 0, { stage_tile(Asrc, A1, 31, tid);
                          stage_tile(Bsrc, B1, 31, tid); }, );
    PHASE(A0, B0, 0, 1, { }, );
    PHASE(A0, B0, 1, 0, { }, );
    PHASE(A0, B0, 1, 1, { }, VM0);
    PHASE(A1, B1, 0, 0, { }, );
    PHASE(A1, B1, 0, 1, { }, );
    PHASE(A1, B1, 1, 0, { }, );
    PHASE(A1, B1, 1, 1, { }, );
#undef PHASE
#undef VM0

  } else {
    // ================= boundary tiles (<=3/64): masked-sum over experts =======
    u16* LA = Lds;
    u16* LB = Lds + TSZ;
    const int r    = tid >> 3;
    const int schk = (tid & 7) ^ (r & 7);
    for (int e = e_lo; e <= e_hi; ++e) {
      const u16* Bsrc = Wb + (size_t)e * QKV_OUT * HIDDEN + (size_t)col0 * HIDDEN;
      bool keep[4];
#pragma unroll
      for (int q = 0; q < 4; ++q) keep[q] = (mm[row0 + q * 64 + r] == e);
      for (int kt = 0; kt < NT; ++kt) {
#pragma unroll
        for (int q = 0; q < 4; ++q) stage_q(Bsrc, LB, kt, q, tid);
#pragma unroll
        for (int q = 0; q < 4; ++q) {
          uint4 v = make_uint4(0u, 0u, 0u, 0u);
          if (keep[q])
            v = *(const uint4*)&Xb[(size_t)(row0 + q * 64 + r) * HIDDEN + kt * BK + schk * 8];
          *(uint4*)&LA[(q * 64 + r) * BK + (tid & 7) * 8] = v;   // phys-linear write
        }
        __syncthreads();   // drains vmcnt+lgkmcnt (slow path: correctness first)
#pragma unroll
        for (int ks = 0; ks < 2; ++ks) {
          const int chunk = ks * 4 + (lane >> 4);
          bf16x8 af[8], bfr[4];
#pragma unroll
          for (int m = 0; m < 8; ++m)
            af[m] = *(const bf16x8*)&LA[lds_off(wr * 128 + m * 16 + (lane & 15), chunk)];
#pragma unroll
          for (int n = 0; n < 4; ++n)
            bfr[n] = *(const bf16x8*)&LB[lds_off(wc * 64 + n * 16 + (lane & 15), chunk)];
#pragma unroll
          for (int m = 0; m < 8; ++m)
#pragma unroll
            for (int n = 0; n < 4; ++n)
              acc[m][n] = __builtin_amdgcn_mfma_f32_16x16x32_bf16(af[m], bfr[n], acc[m][n], 0, 0, 0);
        }
        __syncthreads();
      }
    }
  }

  // ---- epilogue: C/D layout col=lane&15, row=(lane>>4)*4+j (R3-verified) ----
#pragma unroll
  for (int m = 0; m < 8; ++m)
#pragma unroll
    for (int n = 0; n < 4; ++n) {
      f32x4 c = acc[m][n];
      int r0 = row0 + wr * 128 + m * 16 + (lane >> 4) * 4;
      int cc = col0 + wc * 64 + n * 16 + (lane & 15);
#pragma unroll
      for (int j = 0; j < 4; ++j)
        out[(size_t)(r0 + j) * QKV_OUT + cc] = c[j];
    }
}

// ---------------- launch ----------------

extern "C" void kernel_launch(void* const* d_in, const int* in_sizes, int n_in,
                              void* d_out, int out_size, void* d_ws, size_t ws_size,
                              hipStream_t stream) {
  const float* x  = (const float*)d_in[0];
  const float* W  = (const float*)d_in[1];
  const int*   mm = (const int*)d_in[2];
  float* out = (float*)d_out;

  u16* Xb = (u16*)d_ws;                              // 67.1 MB bf16 x
  u16* Wb = Xb + (size_t)TOKENS * HIDDEN;            // 50.3 MB bf16 W

  const long ntot8 = NX8 + NW8;                      // 7,340,032 chunks
  cvt_all<<<(int)(ntot8 / 256), 256, 0, stream>>>(x, W, Xb, Wb);

  hipFuncSetAttribute((const void*)moe_qkv_gemm,
                      hipFuncAttributeMaxDynamicSharedMemorySize, 131072);
  moe_qkv_gemm<<<NBLK, 512, 131072, stream>>>(Xb, Wb, mm, out);
}